// Round 1
// baseline (198.867 us; speedup 1.0000x reference)
//
#include <hip/hip_runtime.h>

#define DIM 64
#define NCODES 512

// Prep: transpose embeddings (D,K) -> ET (K,D) row-major, compute ||e_k||^2,
// zero the loss accumulator slot in d_out. Runs every launch (graph-safe).
__global__ __launch_bounds__(64) void vq_prep(const float* __restrict__ emb,
                                              float* __restrict__ et,
                                              float* __restrict__ norms,
                                              float* __restrict__ loss_slot) {
  const int k = blockIdx.x * 64 + threadIdx.x;  // 8 blocks x 64 threads = 512
  if (blockIdx.x == 0 && threadIdx.x == 0) loss_slot[0] = 0.0f;
  float s = 0.0f;
#pragma unroll
  for (int d = 0; d < DIM; ++d) {
    const float v = emb[d * NCODES + k];  // lanes k consecutive -> coalesced
    et[k * DIM + d] = v;
    s = fmaf(v, v, s);
  }
  norms[k] = s;
}

// Main: 512 threads/block. Threads 0..255 handle rows (codes 0..255),
// threads 256..511 handle the same rows (codes 256..511). Combine via LDS.
__global__ __launch_bounds__(512) void vq_main(const float* __restrict__ x,
                                               const float* __restrict__ et,
                                               const float* __restrict__ norms,
                                               float* __restrict__ out,
                                               float* __restrict__ loss,
                                               float lscale) {
  __shared__ float sbest[256];
  __shared__ int sidx[256];

  const int tid = threadIdx.x;
  const int row_in_block = tid & 255;
  // wave-uniform by construction (256-granular >= 64-granular); force SGPR
  const int kbase = __builtin_amdgcn_readfirstlane((tid >> 8) * (NCODES / 2));
  const int n = blockIdx.x * 256 + row_in_block;

  // x row resident in 64 VGPRs
  float xr[DIM];
  {
    const float4* __restrict__ xv = (const float4*)(x + (size_t)n * DIM);
#pragma unroll
    for (int i = 0; i < DIM / 4; ++i) ((float4*)xr)[i] = xv[i];
  }

  float best = 3.402823e38f;
  int bestk = kbase;
  for (int kk = 0; kk < NCODES / 2; ++kk) {
    const int k = kbase + kk;  // wave-uniform -> ET row via s_load, fmac w/ SGPR src
    const float* __restrict__ e = et + (size_t)k * DIM;
    float a0 = 0.f, a1 = 0.f, a2 = 0.f, a3 = 0.f;
#pragma unroll
    for (int d = 0; d < DIM; d += 4) {
      a0 = fmaf(xr[d + 0], e[d + 0], a0);
      a1 = fmaf(xr[d + 1], e[d + 1], a1);
      a2 = fmaf(xr[d + 2], e[d + 2], a2);
      a3 = fmaf(xr[d + 3], e[d + 3], a3);
    }
    // ||x||^2 dropped: constant per row, argmin-invariant
    const float dist = norms[k] - 2.0f * ((a0 + a1) + (a2 + a3));
    if (dist < best) { best = dist; bestk = k; }  // strict <: first-index ties
  }

  if (kbase != 0) { sbest[row_in_block] = best; sidx[row_in_block] = bestk; }
  __syncthreads();
  if (kbase == 0) {
    const float b1 = sbest[row_in_block];
    const int k1 = sidx[row_in_block];
    if (b1 < best) { best = b1; bestk = k1; }  // strict <: lower half wins ties

    // Epilogue: gather winning code row, write out, accumulate loss
    const float* __restrict__ e = et + (size_t)bestk * DIM;  // divergent gather
    float* __restrict__ o = out + (size_t)n * DIM;
    float lsum = 0.f;
#pragma unroll
    for (int d = 0; d < DIM; d += 4) {
      const float4 q = *(const float4*)(e + d);
      *(float4*)(o + d) = q;
      const float d0 = xr[d + 0] - q.x;
      const float d1 = xr[d + 1] - q.y;
      const float d2 = xr[d + 2] - q.z;
      const float d3 = xr[d + 3] - q.w;
      lsum = fmaf(d0, d0, lsum);
      lsum = fmaf(d1, d1, lsum);
      lsum = fmaf(d2, d2, lsum);
      lsum = fmaf(d3, d3, lsum);
    }
#pragma unroll
    for (int off = 32; off > 0; off >>= 1) lsum += __shfl_down(lsum, off, 64);
    if ((tid & 63) == 0) atomicAdd(loss, lsum * lscale);
  }
}

extern "C" void kernel_launch(void* const* d_in, const int* in_sizes, int n_in,
                              void* d_out, int out_size, void* d_ws, size_t ws_size,
                              hipStream_t stream) {
  const float* x = (const float*)d_in[0];        // (64,32,32,64) fp32
  const float* emb = (const float*)d_in[1];      // (64,512) fp32
  float* out = (float*)d_out;                    // out (4194304) + loss (1)

  const int nrows = in_sizes[0] / DIM;           // 65536
  float* et = (float*)d_ws;                      // 512*64 floats = 128 KiB
  float* norms = et + NCODES * DIM;              // 512 floats
  float* loss = out + (out_size - 1);

  vq_prep<<<NCODES / 64, 64, 0, stream>>>(emb, et, norms, loss);

  const float lscale = 1.25f / (float)(nrows * DIM);  // (1+beta)/numel
  vq_main<<<nrows / 256, 512, 0, stream>>>(x, et, norms, out, loss, lscale);
}

// Round 3
// 172.047 us; speedup vs baseline: 1.1559x; 1.1559x over previous
//
#include <hip/hip_runtime.h>

#define DIM 64
#define NCODES 512
#define ROWS_PB 64
#define XPAD 68  // 64 + 4: breaks LDS bank alignment, keeps 16B alignment for b128

// Prep: transpose embeddings (D,K) -> ET (K,D) row-major, compute ||e_k||^2,
// zero the loss accumulator slot in d_out. Runs every launch (graph-safe).
__global__ __launch_bounds__(64) void vq_prep(const float* __restrict__ emb,
                                              float* __restrict__ et,
                                              float* __restrict__ norms,
                                              float* __restrict__ loss_slot) {
  const int k = blockIdx.x * 64 + threadIdx.x;  // 8 blocks x 64 threads = 512
  if (blockIdx.x == 0 && threadIdx.x == 0) loss_slot[0] = 0.0f;
  float s = 0.0f;
#pragma unroll
  for (int d = 0; d < DIM; ++d) {
    const float v = emb[d * NCODES + k];  // lanes k consecutive -> coalesced
    et[k * DIM + d] = v;
    s = fmaf(v, v, s);
  }
  norms[k] = s;
}

// Main: 512 threads = 8 waves per block. Wave g handles 64 rows (one per lane)
// against code group [g*64, (g+1)*64). Grid = nrows/64 blocks -> ~4 blocks/CU.
__global__ __launch_bounds__(512) void vq_main(const float* __restrict__ x,
                                               const float* __restrict__ et,
                                               const float* __restrict__ norms,
                                               float* __restrict__ out,
                                               float* __restrict__ loss,
                                               float lscale) {
  __shared__ float sx[ROWS_PB * XPAD];  // 17408 B staged x rows
  __shared__ float sbest[8][64];
  __shared__ int sidx[8][64];

  const int tid = threadIdx.x;
  const int lane = tid & 63;
  const int wid = tid >> 6;  // wave id 0..7, wave-uniform
  const int kbase = __builtin_amdgcn_readfirstlane(wid * 64);

  // Cooperative coalesced staging: tile = 64 rows x 64 floats = 1024 float4s,
  // 2 per thread (was 8 -> 4x OOB, round-2 abort)
  {
    const float4* __restrict__ src =
        (const float4*)(x + (size_t)blockIdx.x * ROWS_PB * DIM);
#pragma unroll
    for (int j = 0; j < 2; ++j) {
      const int f = tid + j * 512;          // float4 index 0..1023
      const int r = f >> 4;                 // row 0..63 (16 float4s per row)
      const int c = (f & 15) << 2;          // col 0..60 step 4
      const float4 v = src[f];
      *(float4*)&sx[r * XPAD + c] = v;      // (r*68+c)%4==0 -> 16B aligned
    }
  }
  __syncthreads();

  // x row resident in 64 VGPRs (read from LDS, padded stride)
  float xr[DIM];
#pragma unroll
  for (int i = 0; i < DIM / 4; ++i)
    ((float4*)xr)[i] = *(const float4*)&sx[lane * XPAD + i * 4];

  float best = 3.402823e38f;
  int bestk = kbase;
  for (int kk = 0; kk < NCODES / 8; ++kk) {
    const int k = kbase + kk;  // wave-uniform -> ET row via s_load
    const float* __restrict__ e = et + (size_t)k * DIM;
    float a0 = 0.f, a1 = 0.f, a2 = 0.f, a3 = 0.f;
#pragma unroll
    for (int d = 0; d < DIM; d += 4) {
      a0 = fmaf(xr[d + 0], e[d + 0], a0);
      a1 = fmaf(xr[d + 1], e[d + 1], a1);
      a2 = fmaf(xr[d + 2], e[d + 2], a2);
      a3 = fmaf(xr[d + 3], e[d + 3], a3);
    }
    // ||x||^2 dropped: constant per row, argmin-invariant
    const float dist = norms[k] - 2.0f * ((a0 + a1) + (a2 + a3));
    if (dist < best) { best = dist; bestk = k; }  // strict <: first-index ties
  }

  sbest[wid][lane] = best;
  sidx[wid][lane] = bestk;
  __syncthreads();

  if (wid == 0) {
    // Combine 8 code groups in ascending-k order; strict < keeps lowest k
    float fb = best;
    int fk = bestk;
#pragma unroll
    for (int g = 1; g < 8; ++g) {
      const float b = sbest[g][lane];
      const int kg = sidx[g][lane];
      if (b < fb) { fb = b; fk = kg; }
    }

    const int n = blockIdx.x * ROWS_PB + lane;
    const float* __restrict__ e = et + (size_t)fk * DIM;  // divergent gather
    float* __restrict__ o = out + (size_t)n * DIM;
    float lsum = 0.f;
#pragma unroll
    for (int d = 0; d < DIM; d += 4) {
      const float4 q = *(const float4*)(e + d);
      *(float4*)(o + d) = q;
      const float d0 = xr[d + 0] - q.x;
      const float d1 = xr[d + 1] - q.y;
      const float d2 = xr[d + 2] - q.z;
      const float d3 = xr[d + 3] - q.w;
      lsum = fmaf(d0, d0, lsum);
      lsum = fmaf(d1, d1, lsum);
      lsum = fmaf(d2, d2, lsum);
      lsum = fmaf(d3, d3, lsum);
    }
#pragma unroll
    for (int off = 32; off > 0; off >>= 1) lsum += __shfl_down(lsum, off, 64);
    if (lane == 0) atomicAdd(loss, lsum * lscale);
  }
}

extern "C" void kernel_launch(void* const* d_in, const int* in_sizes, int n_in,
                              void* d_out, int out_size, void* d_ws, size_t ws_size,
                              hipStream_t stream) {
  const float* x = (const float*)d_in[0];    // (64,32,32,64) fp32
  const float* emb = (const float*)d_in[1];  // (64,512) fp32
  float* out = (float*)d_out;                // out (4194304) + loss (1)

  const int nrows = in_sizes[0] / DIM;       // 65536
  float* et = (float*)d_ws;                  // 512*64 floats = 128 KiB
  float* norms = et + NCODES * DIM;          // 512 floats
  float* loss = out + (out_size - 1);

  vq_prep<<<NCODES / 64, 64, 0, stream>>>(emb, et, norms, loss);

  const float lscale = 1.25f / (float)(nrows * DIM);  // (1+beta)/numel
  vq_main<<<nrows / ROWS_PB, 512, 0, stream>>>(x, et, norms, out, loss, lscale);
}

// Round 4
// 145.464 us; speedup vs baseline: 1.3671x; 1.1827x over previous
//
#include <hip/hip_runtime.h>

#define DIM 64
#define NCODES 512
#define ROWS_PB 128   // rows per block (2 per thread-lane)
#define XPAD 68       // 64+4: spreads LDS bank-quads, keeps 16B alignment

// Prep: LDS-tile transpose emb (D,K)->ET (K,D) + ||e||^2 + zero loss slot.
// 8 blocks x 256 threads; block b owns codes [64b, 64b+64). Coalesced R+W.
__global__ __launch_bounds__(256) void vq_prep(const float* __restrict__ emb,
                                               float* __restrict__ et,
                                               float* __restrict__ norms,
                                               float* __restrict__ loss_slot) {
  __shared__ float T[64][65];  // T[d][k_local], +1 pad
  const int tid = threadIdx.x;
  const int k0 = blockIdx.x * 64;
  if (blockIdx.x == 0 && tid == 0) loss_slot[0] = 0.0f;
#pragma unroll
  for (int j = 0; j < 16; ++j) {  // 64 dims x 64 codes, coalesced over k
    const int d = (tid >> 6) + j * 4;
    const int kl = tid & 63;
    T[d][kl] = emb[d * NCODES + k0 + kl];
  }
  __syncthreads();
#pragma unroll
  for (int j = 0; j < 4; ++j) {  // 1024 float4 writes, coalesced
    const int f = tid + j * 256;
    const int kl = f >> 4;
    const int d4 = (f & 15) << 2;
    float4 q;
    q.x = T[d4 + 0][kl]; q.y = T[d4 + 1][kl];
    q.z = T[d4 + 2][kl]; q.w = T[d4 + 3][kl];
    *(float4*)&et[(size_t)(k0 + kl) * DIM + d4] = q;
  }
  if (tid < 64) {
    float s = 0.0f;
#pragma unroll
    for (int d = 0; d < DIM; ++d) s = fmaf(T[d][tid], T[d][tid], s);
    norms[k0 + tid] = s;
  }
}

// Main: 256 threads = 4 waves. Wave g scans codes [128g,128g+128) for 128 rows
// (2 rows per lane, x resident in 128 VGPRs). 512 blocks -> 3 blocks/CU.
__global__ __launch_bounds__(256, 3) void vq_main(const float* __restrict__ x,
                                                  const float* __restrict__ et,
                                                  const float* __restrict__ norms,
                                                  float* __restrict__ out,
                                                  float* __restrict__ loss,
                                                  float lscale) {
  __shared__ float sx[ROWS_PB * XPAD];  // 34816 B staged x rows
  __shared__ float sbest[4][ROWS_PB];
  __shared__ int sidx[4][ROWS_PB];
  __shared__ float sxn[ROWS_PB];
  __shared__ int sfk[ROWS_PB];

  const int tid = threadIdx.x;
  const int lane = tid & 63;
  const int wid = tid >> 6;  // 0..3, wave-uniform
  const int kbase = __builtin_amdgcn_readfirstlane(wid * (NCODES / 4));

  // Stage 128 rows x 64 floats = 2048 float4s, 8 per thread, coalesced
  {
    const float4* __restrict__ src =
        (const float4*)(x + (size_t)blockIdx.x * ROWS_PB * DIM);
#pragma unroll
    for (int j = 0; j < 8; ++j) {
      const int f = tid + j * 256;         // 0..2047
      const int r = f >> 4;                // row 0..127
      const int c = (f & 15) << 2;         // col 0..60
      *(float4*)&sx[r * XPAD + c] = src[f];
    }
  }
  __syncthreads();

  // Two x rows per lane, resident in VGPRs
  float xr0[DIM], xr1[DIM];
#pragma unroll
  for (int i = 0; i < DIM / 4; ++i) {
    ((float4*)xr0)[i] = *(const float4*)&sx[lane * XPAD + i * 4];
    ((float4*)xr1)[i] = *(const float4*)&sx[(lane + 64) * XPAD + i * 4];
  }
  if (wid == 0) {  // per-row ||x||^2 for the loss identity ||x-q||^2 = best + ||x||^2
    float s0 = 0.f, s1 = 0.f;
#pragma unroll
    for (int d = 0; d < DIM; ++d) {
      s0 = fmaf(xr0[d], xr0[d], s0);
      s1 = fmaf(xr1[d], xr1[d], s1);
    }
    sxn[lane] = s0;
    sxn[lane + 64] = s1;
  }

  float best0 = 3.402823466e38f, best1 = 3.402823466e38f;
  int bk0 = kbase, bk1 = kbase;
  for (int kk = 0; kk < NCODES / 4; ++kk) {
    const int k = kbase + kk;  // wave-uniform -> s_load_dwordx16 ET row (SGPRs)
    const float* __restrict__ e = et + (size_t)k * DIM;
    float a0 = 0.f, a1 = 0.f, a2 = 0.f, a3 = 0.f;
    float b0 = 0.f, b1 = 0.f, b2 = 0.f, b3 = 0.f;
#pragma unroll
    for (int d = 0; d < DIM; d += 4) {  // 128 fma vs one 256B scalar fetch
      a0 = fmaf(xr0[d + 0], e[d + 0], a0); b0 = fmaf(xr1[d + 0], e[d + 0], b0);
      a1 = fmaf(xr0[d + 1], e[d + 1], a1); b1 = fmaf(xr1[d + 1], e[d + 1], b1);
      a2 = fmaf(xr0[d + 2], e[d + 2], a2); b2 = fmaf(xr1[d + 2], e[d + 2], b2);
      a3 = fmaf(xr0[d + 3], e[d + 3], a3); b3 = fmaf(xr1[d + 3], e[d + 3], b3);
    }
    const float nk = norms[k];  // ||x||^2 dropped: argmin-invariant
    const float d0 = nk - 2.0f * ((a0 + a1) + (a2 + a3));
    const float d1 = nk - 2.0f * ((b0 + b1) + (b2 + b3));
    if (d0 < best0) { best0 = d0; bk0 = k; }  // strict <: first-index ties
    if (d1 < best1) { best1 = d1; bk1 = k; }
  }

  sbest[wid][lane] = best0;      sidx[wid][lane] = bk0;
  sbest[wid][lane + 64] = best1; sidx[wid][lane + 64] = bk1;
  __syncthreads();

  // Combine 4 code groups (ascending k, strict <) + loss; waves 0,1 only
  float lsum = 0.f;
  if (tid < ROWS_PB) {  // wave-uniform branch
    float fb = sbest[0][tid];
    int fk = sidx[0][tid];
#pragma unroll
    for (int g = 1; g < 4; ++g) {
      const float b = sbest[g][tid];
      if (b < fb) { fb = b; fk = sidx[g][tid]; }
    }
    sfk[tid] = fk;
    lsum = fb + sxn[tid];  // = ||x - q||^2 exactly (up to fp rounding)
  }
#pragma unroll
  for (int off = 32; off > 0; off >>= 1) lsum += __shfl_down(lsum, off, 64);
  if (tid < ROWS_PB && lane == 0) atomicAdd(loss, lsum * lscale);
  __syncthreads();

  // Distributed epilogue: gather winning rows, coalesced float4 store
  {
    float* __restrict__ o = out + (size_t)blockIdx.x * ROWS_PB * DIM;
#pragma unroll
    for (int j = 0; j < 8; ++j) {
      const int f = tid + j * 256;
      const int r = f >> 4;
      const int c = (f & 15) << 2;
      const int k = sfk[r];  // broadcast within 16-lane groups
      *(float4*)&o[(size_t)r * DIM + c] = *(const float4*)&et[(size_t)k * DIM + c];
    }
  }
}

extern "C" void kernel_launch(void* const* d_in, const int* in_sizes, int n_in,
                              void* d_out, int out_size, void* d_ws, size_t ws_size,
                              hipStream_t stream) {
  const float* x = (const float*)d_in[0];    // (64,32,32,64) fp32
  const float* emb = (const float*)d_in[1];  // (64,512) fp32
  float* out = (float*)d_out;                // out (4194304) + loss (1)

  const int nrows = in_sizes[0] / DIM;       // 65536
  float* et = (float*)d_ws;                  // 512*64 floats = 128 KiB
  float* norms = et + NCODES * DIM;          // 512 floats
  float* loss = out + (out_size - 1);

  vq_prep<<<NCODES / 64, 256, 0, stream>>>(emb, et, norms, loss);

  const float lscale = 1.25f / (float)(nrows * DIM);  // (1+beta)/numel
  vq_main<<<nrows / ROWS_PB, 256, 0, stream>>>(x, et, norms, out, loss, lscale);
}

// Round 5
// 145.350 us; speedup vs baseline: 1.3682x; 1.0008x over previous
//
#include <hip/hip_runtime.h>

#define DIM 64
#define NCODES 512
#define ROWS_PB 64
#define XPAD 68   // 64+4: keeps 16B alignment for float4 LDS ops
#define NW 8      // waves per block
#define CPW 64    // codes per wave

// Prep: LDS-tile transpose emb (D,K)->ET (K,D) + ||e||^2 + zero loss slot.
__global__ __launch_bounds__(256) void vq_prep(const float* __restrict__ emb,
                                               float* __restrict__ et,
                                               float* __restrict__ norms,
                                               float* __restrict__ loss_slot) {
  __shared__ float T[64][65];
  const int tid = threadIdx.x;
  const int k0 = blockIdx.x * 64;
  if (blockIdx.x == 0 && tid == 0) loss_slot[0] = 0.0f;
#pragma unroll
  for (int j = 0; j < 16; ++j) {
    const int d = (tid >> 6) + j * 4;
    const int kl = tid & 63;
    T[d][kl] = emb[d * NCODES + k0 + kl];
  }
  __syncthreads();
#pragma unroll
  for (int j = 0; j < 4; ++j) {
    const int f = tid + j * 256;
    const int kl = f >> 4;
    const int d4 = (f & 15) << 2;
    float4 q;
    q.x = T[d4 + 0][kl]; q.y = T[d4 + 1][kl];
    q.z = T[d4 + 2][kl]; q.w = T[d4 + 3][kl];
    *(float4*)&et[(size_t)(k0 + kl) * DIM + d4] = q;
  }
  if (tid < 64) {
    float s = 0.0f;
#pragma unroll
    for (int d = 0; d < DIM; ++d) s = fmaf(T[d][tid], T[d][tid], s);
    norms[k0 + tid] = s;
  }
}

// Main: 512 threads = 8 waves; 64 rows/block (row = lane, same rows for all
// waves); wave w scans codes [64w, 64w+64). Grid = 1024 blocks -> 4/CU.
__global__ __launch_bounds__(512, 4) void vq_main(const float* __restrict__ x,
                                                  const float* __restrict__ et,
                                                  const float* __restrict__ norms,
                                                  float* __restrict__ out,
                                                  float* __restrict__ loss,
                                                  float lscale) {
  __shared__ float pool[ROWS_PB * XPAD];  // 17408 B; reused post-k-loop
  float* sbest = pool;                    // [512]
  int* sidx = (int*)(pool + 512);         // [512]
  int* sfk = (int*)(pool + 1024);         // [64]

  const int tid = threadIdx.x;
  const int lane = tid & 63;
  const int wid = tid >> 6;
  const int kbase = __builtin_amdgcn_readfirstlane(wid * CPW);

  // Coalesced staging: 64 rows x 16 float4 = 1024 float4s, 2/thread
  {
    const float4* __restrict__ src =
        (const float4*)(x + (size_t)blockIdx.x * ROWS_PB * DIM);
#pragma unroll
    for (int j = 0; j < 2; ++j) {
      const int f = tid + j * 512;
      const int r = f >> 4;
      const int c = (f & 15) << 2;
      *(float4*)&pool[r * XPAD + c] = src[f];
    }
  }
  __syncthreads();

  // x row -> VGPRs (row = lane; all 8 waves read the same 64 rows)
  float xr[DIM];
#pragma unroll
  for (int i = 0; i < DIM / 4; ++i)
    ((float4*)xr)[i] = *(const float4*)&pool[lane * XPAD + i * 4];
  __syncthreads();
  // Volatile clobber of the staging region: compiler can no longer prove the
  // staged x survives, so xr MUST stay in VGPRs (round-4 bug: VGPR=84 showed
  // xr was demoted to per-iteration LDS re-reads -> LDS-pipe-bound, VALU 39%).
  // Same thread writes pool[tid] again below (sbest) -> no race, no DSE.
  ((volatile float*)pool)[tid] = 0.0f;

  float best = 3.402823466e38f;
  int bestk = kbase;
  for (int kk = 0; kk < CPW; ++kk) {
    const int k = __builtin_amdgcn_readfirstlane(kbase + kk);  // force SGPR path
    const float* __restrict__ e = et + (size_t)k * DIM;  // s_load_dwordx16 x4
    float a0 = 0.f, a1 = 0.f, a2 = 0.f, a3 = 0.f;
#pragma unroll
    for (int d = 0; d < DIM; d += 4) {
      a0 = fmaf(xr[d + 0], e[d + 0], a0);
      a1 = fmaf(xr[d + 1], e[d + 1], a1);
      a2 = fmaf(xr[d + 2], e[d + 2], a2);
      a3 = fmaf(xr[d + 3], e[d + 3], a3);
    }
    // ||x||^2 dropped: constant per row, argmin-invariant
    const float dist = fmaf((a0 + a1) + (a2 + a3), -2.0f, norms[k]);
    if (dist < best) { best = dist; bestk = k; }  // strict <: first-index ties
  }

  sbest[tid] = best;  // tid == wid*64+lane: same address as the clobber
  sidx[tid] = bestk;
  __syncthreads();

  if (wid == 0) {
    // Combine 8 code groups in ascending-k order; strict < keeps lowest k
    float fb = sbest[lane];
    int fk = sidx[lane];
#pragma unroll
    for (int g = 1; g < NW; ++g) {
      const float b = sbest[g * 64 + lane];
      if (b < fb) { fb = b; fk = sidx[g * 64 + lane]; }
    }
    sfk[lane] = fk;
    // loss contribution: ||x-q||^2 = best_dist + ||x||^2 (||x||^2 in-register)
    float xn = 0.f;
#pragma unroll
    for (int d = 0; d < DIM; ++d) xn = fmaf(xr[d], xr[d], xn);
    float lsum = fb + xn;
#pragma unroll
    for (int off = 32; off > 0; off >>= 1) lsum += __shfl_down(lsum, off, 64);
    if (lane == 0) atomicAdd(loss, lsum * lscale);
  }
  __syncthreads();

  // Distributed epilogue: gather winning rows, coalesced float4 store
  {
    float* __restrict__ o = out + (size_t)blockIdx.x * ROWS_PB * DIM;
#pragma unroll
    for (int j = 0; j < 2; ++j) {
      const int f = tid + j * 512;
      const int r = f >> 4;
      const int c = (f & 15) << 2;
      const int k = sfk[r];
      *(float4*)&o[(size_t)r * DIM + c] = *(const float4*)&et[(size_t)k * DIM + c];
    }
  }
}

extern "C" void kernel_launch(void* const* d_in, const int* in_sizes, int n_in,
                              void* d_out, int out_size, void* d_ws, size_t ws_size,
                              hipStream_t stream) {
  const float* x = (const float*)d_in[0];    // (64,32,32,64) fp32
  const float* emb = (const float*)d_in[1];  // (64,512) fp32
  float* out = (float*)d_out;                // out (4194304) + loss (1)

  const int nrows = in_sizes[0] / DIM;       // 65536
  float* et = (float*)d_ws;                  // 512*64 floats = 128 KiB
  float* norms = et + NCODES * DIM;          // 512 floats
  float* loss = out + (out_size - 1);

  vq_prep<<<NCODES / 64, 256, 0, stream>>>(emb, et, norms, loss);

  const float lscale = 1.25f / (float)(nrows * DIM);  // (1+beta)/numel
  vq_main<<<nrows / ROWS_PB, 512, 0, stream>>>(x, et, norms, out, loss, lscale);
}